// Round 16
// baseline (203.035 us; speedup 1.0000x reference)
//
#include <hip/hip_runtime.h>
#include <math.h>

// Problem constants (match reference)
#define B_    2
#define T_    2048
#define C_    1024
#define HS_   8
#define DS_   32
#define HL_   8
#define DL_   128
#define HD_   64
#define WINS_ 256
#define WINL_ 1024
#define NALL_ 3584   // 512 (qk_s) + 512 (v_s) + 2048 (qk_l) + 512 (v_l)

typedef __bf16 bf16x8 __attribute__((ext_vector_type(8)));
typedef float floatx4 __attribute__((ext_vector_type(4)));

__device__ __forceinline__ ushort f2bf(float f) {
    union { float f; unsigned u; } v; v.f = f;
    unsigned r = v.u + 0x7fff + ((v.u >> 16) & 1);  // RNE
    return (ushort)(r >> 16);
}
__device__ __forceinline__ float bf2f(ushort u) {
    union { unsigned u; float f; } v; v.u = ((unsigned)u) << 16;
    return v.f;
}

// ---- DPP 16-lane butterfly reductions (VALU latency, no LDS) ----
#define DPP_STEP(x, ctrl, op)                                                \
    {                                                                        \
        float _t = __builtin_bit_cast(                                       \
            float, __builtin_amdgcn_update_dpp(                              \
                       0, __builtin_bit_cast(int, (x)), (ctrl), 0xf, 0xf,    \
                       true));                                               \
        (x) = op((x), _t);                                                   \
    }
__device__ __forceinline__ float dpp_max16(float x) {
    DPP_STEP(x, 0xB1, fmaxf);
    DPP_STEP(x, 0x4E, fmaxf);
    DPP_STEP(x, 0x141, fmaxf);
    DPP_STEP(x, 0x140, fmaxf);
    return x;
}
__device__ __forceinline__ float dpp_add16(float x) {
#define FADD_(a, b) ((a) + (b))
    DPP_STEP(x, 0xB1, FADD_);
    DPP_STEP(x, 0x4E, FADD_);
    DPP_STEP(x, 0x141, FADD_);
    DPP_STEP(x, 0x140, FADD_);
#undef FADD_
    return x;
}

// async global->LDS, 16B per lane. LDS dest = wave-uniform base + lane*16.
__device__ __forceinline__ void gload_lds16(const void* g, void* l) {
    __builtin_amdgcn_global_load_lds(
        (const __attribute__((address_space(1))) void*)g,
        (__attribute__((address_space(3))) void*)l, 16, 0, 0);
}

// ---------------------------------------------------------------------------
// Fused prep: blocks [0,4096) convert x fp32->bf16; blocks [4096,8704)
// transpose+convert the five weight matrices (K=1024 each).
// ---------------------------------------------------------------------------
__global__ __launch_bounds__(256) void prep(
    const float* __restrict__ x, ushort* __restrict__ x16,
    const float* __restrict__ Wqk_s, const float* __restrict__ Wv_s,
    const float* __restrict__ Wqk_l, const float* __restrict__ Wv_l,
    const float* __restrict__ Wproj, ushort* __restrict__ WallT,
    ushort* __restrict__ WprojT) {
    __shared__ float t[32][33];
    int bid = blockIdx.x;
    if (bid < 4096) {
        const int i = bid * 256 + threadIdx.x;
        float4 v = ((const float4*)x)[i];
        ushort4 o;
        o.x = f2bf(v.x); o.y = f2bf(v.y); o.z = f2bf(v.z); o.w = f2bf(v.w);
        ((ushort4*)x16)[i] = o;
        return;
    }
    bid -= 4096;
    const float* W; ushort* WT; int N, rowoff;
    if (bid < 512)       { W = Wqk_s; WT = WallT;  N = 512;  rowoff = 0; }
    else if (bid < 1024) { bid -= 512;  W = Wv_s;  WT = WallT;  N = 512;  rowoff = 512; }
    else if (bid < 3072) { bid -= 1024; W = Wqk_l; WT = WallT;  N = 2048; rowoff = 1024; }
    else if (bid < 3584) { bid -= 3072; W = Wv_l;  WT = WallT;  N = 512;  rowoff = 3072; }
    else                 { bid -= 3584; W = Wproj; WT = WprojT; N = 1024; rowoff = 0; }
    const int nt = N / 32;
    const int n0 = (bid % nt) * 32;
    const int k0 = (bid / nt) * 32;
    const int tx = threadIdx.x & 31;
    const int ty = threadIdx.x >> 5;  // 0..7
#pragma unroll
    for (int i = 0; i < 4; ++i)
        t[ty + 8 * i][tx] = W[(size_t)(k0 + ty + 8 * i) * N + n0 + tx];
    __syncthreads();
#pragma unroll
    for (int i = 0; i < 4; ++i)
        WT[(size_t)(rowoff + n0 + ty + 8 * i) * 1024 + k0 + tx] =
            f2bf(t[tx][ty + 8 * i]);
}

// ---------------------------------------------------------------------------
// bf16 MFMA GEMM: C[M,N] = A[M,K] bf16 @ BT[N,K] bf16.
// COUNTED-VMCNT PIPELINE (T4, m218): triple-buffered LDS, 2 K-tiles in
// flight; s_waitcnt vmcnt(NLD) + raw s_barrier per K-step (never drain 0).
//   gemm1: 256x128 @ 512T (R10 config). gemm2: 64x64 @ 256T (R9 config).
// NO XCD swizzle (R13: regression in this L3-fit regime).
// __launch_bounds__(TH,4) pins the 128-VGPR cap.
// FUSEV (input projection only): V-column tiles store TRANSPOSED into vt.
// ---------------------------------------------------------------------------
template <int BM, int BN, int TH, typename OT, bool FUSEV>
__global__ __launch_bounds__(TH, 4) void gemm_bf16(const ushort* __restrict__ A,
                                                   const ushort* __restrict__ BT,
                                                   OT* __restrict__ Cm,
                                                   ushort* __restrict__ VT,
                                                   int M, int N, int K) {
    // A rows [0,BM) then B rows [BM,BM+BN), each row 32 ushorts (one K-step)
    __shared__ ushort S[3][(BM + BN) * 32];
    constexpr int WM = TH / 128;             // waves along M (4 or 2)
    constexpr int NI = BM / WM / 16;         // per-wave M frags (4 or 2)
    constexpr int JB = BN / 32;              // per-wave N frags (4 or 2)
    constexpr int NLD = (BM + BN) * 4 / TH;  // gload_lds16 per thread/K-step

    const int tid = threadIdx.x;
    const int m0 = blockIdx.y * BM;
    const int n0 = blockIdx.x * BN;
    const int wave = tid >> 6;
    const int lane = tid & 63;
    const int wm = (wave >> 1) * (BM / WM);
    const int wn = (wave & 1) * (BN / 2);
    const int l15 = lane & 15;
    const int quad = lane >> 4;

    floatx4 acc[NI][JB] = {};

    // per-load staging base pointers (uniform branch per load index)
    const ushort* sbase[NLD];
#pragma unroll
    for (int i = 0; i < NLD; ++i) {
        const int idx = tid + TH * i;
        const int row = idx >> 2;
        const int ch = (idx & 3) * 8;
        sbase[i] = (row < BM) ? A + (size_t)(m0 + row) * K + ch
                              : BT + (size_t)(n0 + row - BM) * K + ch;
    }

#define STAGE(buf, kt)                                                      \
    {                                                                       \
        _Pragma("unroll") for (int i_ = 0; i_ < NLD; ++i_)                  \
            gload_lds16(sbase[i_] + (kt),                                   \
                        &S[buf][(wave * 64 + TH * i_) * 8]);                \
    }

#define COMPUTE(buf)                                                        \
    {                                                                       \
        bf16x8 af[NI], bfr[JB];                                             \
        _Pragma("unroll") for (int i = 0; i < NI; ++i) af[i] =              \
            *(const bf16x8*)&S[buf][(wm + i * 16 + l15) * 32 + quad * 8];   \
        _Pragma("unroll") for (int j = 0; j < JB; ++j) bfr[j] =             \
            *(const bf16x8*)&S[buf][(BM + wn + j * 16 + l15) * 32 +         \
                                    quad * 8];                              \
        _Pragma("unroll") for (int i = 0; i < NI; ++i)                      \
            _Pragma("unroll") for (int j = 0; j < JB; ++j) acc[i][j] =      \
                __builtin_amdgcn_mfma_f32_16x16x32_bf16(af[i], bfr[j],      \
                                                        acc[i][j], 0, 0, 0); \
    }

    // wait until only the NEWEST K-step's loads remain in flight
#define WAIT_CUR()                                                    \
    {                                                                 \
        if constexpr (NLD == 4)                                       \
            asm volatile("s_waitcnt vmcnt(4)" ::: "memory");          \
        else if constexpr (NLD == 3)                                  \
            asm volatile("s_waitcnt vmcnt(3)" ::: "memory");          \
        else                                                          \
            asm volatile("s_waitcnt vmcnt(2)" ::: "memory");          \
    }

    STAGE(0, 0);
    STAGE(1, 32);
    int cur = 0;
    for (int kt = 0; kt + 32 < K; kt += 32) {
        WAIT_CUR();
        __builtin_amdgcn_s_barrier();
        __builtin_amdgcn_sched_barrier(0);
        if (kt + 64 < K) {
            int nxt2 = cur + 2;
            if (nxt2 >= 3) nxt2 -= 3;
            STAGE(nxt2, kt + 64);
        }
        COMPUTE(cur);
        ++cur;
        if (cur == 3) cur = 0;
    }
    asm volatile("s_waitcnt vmcnt(0)" ::: "memory");
    __builtin_amdgcn_s_barrier();
    __builtin_amdgcn_sched_barrier(0);
    COMPUTE(cur);
#undef STAGE
#undef COMPUTE
#undef WAIT_CUR

    // ---- epilogue ----
    bool vtile = false;
    if constexpr (FUSEV)
        vtile = (n0 >= 512 && n0 < 1024) || (n0 >= 3072);

    if (FUSEV && vtile) {
        // transposed store into vt: row = b*1024 + vcol, col = t
#pragma unroll
        for (int i = 0; i < NI; ++i) {
            const int m = m0 + wm + i * 16 + quad * 4;
            const int bb = m >> 11;
            const int t = m & 2047;
#pragma unroll
            for (int j = 0; j < JB; ++j) {
                const int col = n0 + wn + j * 16 + l15;
                const int vcol = (col < 1024) ? (col - 512) : (col - 2560);
                ushort4 val;
                val.x = f2bf(acc[i][j][0]);
                val.y = f2bf(acc[i][j][1]);
                val.z = f2bf(acc[i][j][2]);
                val.w = f2bf(acc[i][j][3]);
                *(ushort4*)&VT[((size_t)(bb * 1024 + vcol)) * T_ + t] = val;
            }
        }
    } else {
#pragma unroll
        for (int i = 0; i < NI; ++i)
#pragma unroll
            for (int j = 0; j < JB; ++j)
#pragma unroll
                for (int r = 0; r < 4; ++r) {
                    const size_t idx =
                        (size_t)(m0 + wm + i * 16 + quad * 4 + r) * N + n0 +
                        wn + j * 16 + l15;
                    if constexpr (sizeof(OT) == 2)
                        Cm[idx] = f2bf(acc[i][j][r]);
                    else
                        Cm[idx] = acc[i][j][r];
                }
    }
}

// ---------------------------------------------------------------------------
// MFMA flash attention core — R11 champion structure + 4-WAY K-SPLIT for
// long heads (this round's change, attacking the tail imbalance:
// OccupancyPercent 32% = avg 10/24 waves/CU because the 768-block grid was
// exactly co-resident with per-block durations 1..9 tiles -> every CU ends
// running its heaviest block alone). 4-way split caps long blocks at
// <=5 tiles; 1280 blocks over 768 slots adds dynamic backfill.
// `part` in [0,4) picks a contiguous quarter of the tile range (cnt=0 ->
// empty branch, self-correcting via m=-1e30/l=0 in combine). Partials for
// parts 0-1 go to po/pm/pl; parts 2-3 to po2/pm2/pl2 (overlaid on
// x16/WallT, which are dead after gemm1 -- stream-ordered, safe). Storage
// ridx reuses the 2-split formula with zs = part&1 on the passed base.
// LDS: Ks 64*(D+8) | VTs 64*72 | Ps 128*72 -> 45056 B => 3 blocks/CU.
// ---------------------------------------------------------------------------
template <int D, int WIN, bool SPLIT>
__device__ __forceinline__ void attn_dev(
    const ushort* __restrict__ act, const ushort* __restrict__ vt,
    ushort* __restrict__ y, ushort* __restrict__ po, float* __restrict__ pm,
    float* __restrict__ pl, float scale2, int qoff, int koff, int head_off,
    int h, int gh, int b, int t0, int zs, int part, ushort* lds) {
    constexpr int STR = D + 8;
    constexpr int VSTR = 72;
    constexpr int PSTR = 72;
    constexpr int NKS = D / 32;
    constexpr int QCH = D / 8;
    constexpr int KCH_TOT = 64 * QCH;            // 16B chunks in a K tile
    constexpr int NKLD = (KCH_TOT + 511) / 512;  // per-thread K loads

    ushort* Ks = lds;
    ushort* VTs = Ks + 64 * STR;
    ushort* Ps = VTs + 64 * VSTR;   // 128 rows

    const int tid = threadIdx.x;
    const int wave = tid >> 6;      // 0..7
    const int lane = tid & 63;
    const int l15 = lane & 15;
    const int quad = lane >> 4;
    const int qmin = t0 + wave * 16;

    int k0s = t0 - WIN + 1;
    if (k0s < 0) k0s = 0;
    k0s &= ~63;

    int ks_begin = k0s, ks_last = t0 + 64;  // queries span t0..t0+127
    if (SPLIT) {
        const int nt = ((t0 + 64 - k0s) >> 6) + 1;
        const int q = nt >> 2;
        const int r = nt & 3;
        const int cnt = q + (part < r ? 1 : 0);
        const int start = part * q + (part < r ? part : r);
        if (cnt == 0) {  // empty quarter: zero partials, done
#pragma unroll
            for (int rr = 0; rr < 4; ++rr) {
                const int t = qmin + quad * 4 + rr;
                const size_t ridx = (((size_t)(zs * 2 + b) * 8 + h) * T_ + t);
                if (l15 == 0) { pm[ridx] = -1e30f; pl[ridx] = 0.f; }
#pragma unroll
                for (int j = 0; j < 4; ++j)
                    po[ridx * 64 + j * 16 + l15] = 0;
            }
            return;
        }
        ks_begin = k0s + start * 64;
        ks_last = k0s + (start + cnt - 1) * 64;
    }

    const ushort* qbase = act + (size_t)(b * T_ + t0) * NALL_ + qoff + h * D;
    const ushort* kbase = act + (size_t)(b * T_) * NALL_ + koff + h * D;
    const ushort* vtb = vt + (size_t)((b * 16 + gh) * HD_) * T_;

    int krow[NKLD], kch[NKLD];
#pragma unroll
    for (int i = 0; i < NKLD; ++i) {
        const int idx = tid + 512 * i;
        krow[i] = idx / QCH;
        kch[i] = idx % QCH;
    }
    const int vd = tid >> 3, vc = (tid & 7) * 8;

    // ---- prefetch first tile into registers ----
    int4 kreg[NKLD], vreg;
#pragma unroll
    for (int i = 0; i < NKLD; ++i)
        if (tid + 512 * i < KCH_TOT)
            kreg[i] = *(const int4*)(kbase +
                                     (size_t)(ks_begin + krow[i]) * NALL_ +
                                     kch[i] * 8);
    vreg = *(const int4*)(vtb + (size_t)vd * T_ + ks_begin + vc);

    // ---- Q direct global -> registers (no LDS round-trip) ----
    bf16x8 qa[NKS];
#pragma unroll
    for (int ks = 0; ks < NKS; ++ks)
        qa[ks] = *(const bf16x8*)(qbase + (size_t)(wave * 16 + l15) * NALL_ +
                                  ks * 32 + quad * 8);

    float m_i[4], l_i[4];
    floatx4 o_acc[4] = {};
#pragma unroll
    for (int r = 0; r < 4; ++r) { m_i[r] = -1e30f; l_i[r] = 0.f; }

    for (int k0 = ks_begin; k0 <= ks_last; k0 += 64) {
        __syncthreads();  // all waves done reading Ks/VTs of prev tile
#pragma unroll
        for (int i = 0; i < NKLD; ++i)
            if (tid + 512 * i < KCH_TOT)
                *(int4*)&Ks[krow[i] * STR + kch[i] * 8] = kreg[i];
        *(int4*)&VTs[vd * VSTR + vc] = vreg;
        __syncthreads();
        if (k0 + 64 <= ks_last) {  // prefetch next tile (overlaps compute)
#pragma unroll
            for (int i = 0; i < NKLD; ++i)
                if (tid + 512 * i < KCH_TOT)
                    kreg[i] = *(const int4*)(kbase +
                                             (size_t)(k0 + 64 + krow[i]) *
                                                 NALL_ +
                                             kch[i] * 8);
            vreg = *(const int4*)(vtb + (size_t)vd * T_ + k0 + 64 + vc);
        }

        // ---- S = Q K^T ----
        floatx4 s[4] = {};
#pragma unroll
        for (int ks = 0; ks < NKS; ++ks) {
#pragma unroll
            for (int j = 0; j < 4; ++j) {
                const bf16x8 bb =
                    *(const bf16x8*)&Ks[(j * 16 + l15) * STR + ks * 32 + quad * 8];
                s[j] = __builtin_amdgcn_mfma_f32_16x16x32_bf16(qa[ks], bb, s[j],
                                                               0, 0, 0);
            }
        }

        // ---- scale (log2 domain) + mask ----
        const bool full = (k0 + 63 <= qmin) && ((qmin + 15) - k0 <= WIN - 1);
        if (full) {
#pragma unroll
            for (int j = 0; j < 4; ++j)
#pragma unroll
                for (int r = 0; r < 4; ++r) s[j][r] *= scale2;
        } else {
#pragma unroll
            for (int j = 0; j < 4; ++j) {
                const int kj = k0 + j * 16 + l15;
#pragma unroll
                for (int r = 0; r < 4; ++r) {
                    const int rel = (qmin + quad * 4 + r) - kj;
                    s[j][r] = (rel < 0 || rel >= WIN) ? -1e30f : s[j][r] * scale2;
                }
            }
        }

        // ---- online softmax (exp2 domain), DPP reductions, defer-max ----
        float rm[4];
#pragma unroll
        for (int r = 0; r < 4; ++r) {
            float t = fmaxf(fmaxf(s[0][r], s[1][r]), fmaxf(s[2][r], s[3][r]));
            rm[r] = dpp_max16(t);
        }
        const bool need = (rm[0] > m_i[0] + 8.f) || (rm[1] > m_i[1] + 8.f) ||
                          (rm[2] > m_i[2] + 8.f) || (rm[3] > m_i[3] + 8.f);
        if (__any(need)) {
#pragma unroll
            for (int r = 0; r < 4; ++r) {
                const float mn = fmaxf(m_i[r], rm[r]);
                const float a = exp2f(m_i[r] - mn);
                m_i[r] = mn;
                l_i[r] *= a;
#pragma unroll
                for (int j = 0; j < 4; ++j) o_acc[j][r] *= a;
            }
        }
#pragma unroll
        for (int r = 0; r < 4; ++r) {
            float sum = 0.f;
#pragma unroll
            for (int j = 0; j < 4; ++j) {
                const float e = exp2f(s[j][r] - m_i[r]);
                sum += e;
                Ps[(wave * 16 + quad * 4 + r) * PSTR + j * 16 + l15] = f2bf(e);
            }
            sum = dpp_add16(sum);
            l_i[r] += sum;
        }

        // ---- PV ----
#pragma unroll
        for (int kks = 0; kks < 2; ++kks) {
            const bf16x8 pa =
                *(const bf16x8*)&Ps[(wave * 16 + l15) * PSTR + kks * 32 + quad * 8];
#pragma unroll
            for (int j = 0; j < 4; ++j) {
                const bf16x8 vb =
                    *(const bf16x8*)&VTs[(j * 16 + l15) * VSTR + kks * 32 + quad * 8];
                o_acc[j] = __builtin_amdgcn_mfma_f32_16x16x32_bf16(pa, vb, o_acc[j],
                                                                   0, 0, 0);
            }
        }
    }

    // ---- epilogue ----
    if (SPLIT) {
#pragma unroll
        for (int r = 0; r < 4; ++r) {
            const int t = qmin + quad * 4 + r;
            const size_t ridx = (((size_t)(zs * 2 + b) * 8 + h) * T_ + t);
            if (l15 == 0) { pm[ridx] = m_i[r]; pl[ridx] = l_i[r]; }
#pragma unroll
            for (int j = 0; j < 4; ++j)
                po[ridx * 64 + j * 16 + l15] = f2bf(o_acc[j][r]);
        }
    } else {
#pragma unroll
        for (int r = 0; r < 4; ++r) {
            const float inv = 1.f / l_i[r];
            ushort* yrow = y + (size_t)(b * T_ + qmin + quad * 4 + r) * C_ +
                           head_off + h * HD_;
#pragma unroll
            for (int j = 0; j < 4; ++j)
                yrow[j * 16 + l15] = f2bf(o_acc[j][r] * inv);
        }
    }
}

// Sorted 1D job grid, QBLK=128, 4-way long split: x<1024 = long quarters
// (t0 desc, part = x&3), x>=1024 = short unsplit (t0 desc). 1280 blocks
// @ 512T over 768 resident slots -> dynamic backfill, heavy first.
__global__ __launch_bounds__(512, 4) void attn_sched(
    const ushort* __restrict__ act, const ushort* __restrict__ vt,
    ushort* __restrict__ y, ushort* __restrict__ po, float* __restrict__ pm,
    float* __restrict__ pl, ushort* __restrict__ po2,
    float* __restrict__ pm2, float* __restrict__ pl2) {
    extern __shared__ ushort smem[];
    int x = blockIdx.x;
    if (x < 1024) {
        const int part = x & 3;
        const int b = (x >> 2) & 1;
        const int h = (x >> 3) & 7;
        const int t0 = (15 - (x >> 6)) * 128;
        ushort* pob = (part < 2) ? po : po2;
        float* pmb = (part < 2) ? pm : pm2;
        float* plb = (part < 2) ? pl : pl2;
        attn_dev<DL_, WINL_, true>(act, vt, y, pob, pmb, plb,
                                   0.12752021352994164f,  // 1/sqrt(128)*log2e
                                   1024, 2048, 512, h, 8 + h, b, t0, part & 1,
                                   part, smem);
    } else {
        x -= 1024;
        const int b = x & 1;
        const int h = (x >> 1) & 7;
        const int t0 = (15 - (x >> 4)) * 128;
        attn_dev<DS_, WINS_, false>(act, vt, y, po, pm, pl,
                                    0.2550404270598833f,  // 1/sqrt(32)*log2e
                                    0, 256, 0, h, h, b, t0, 0, 0, smem);
    }
}

// ---------------------------------------------------------------------------
// Flash-decoding combine for long heads: merge 4 splits' (o,m,l) -> yb16.
// exp2 domain. rows = [b][h][t] (32768); thread = one row x 4 cols.
// Empty quarters carry m=-1e30, l=0 -> e=0 contribution.
// ---------------------------------------------------------------------------
__global__ __launch_bounds__(256) void combine(
    const ushort* __restrict__ po, const float* __restrict__ pm,
    const float* __restrict__ pl, const ushort* __restrict__ po2,
    const float* __restrict__ pm2, const float* __restrict__ pl2,
    ushort* __restrict__ y) {
    const int gid = blockIdx.x * 256 + threadIdx.x;
    const int row = gid >> 4;
    const int cg = (gid & 15) * 4;
    const int b = row >> 14;
    const int h = (row >> 11) & 7;
    const int t = row & 2047;

    const float m0 = pm[row], m1 = pm[32768 + row];
    const float m2 = pm2[row], m3 = pm2[32768 + row];
    const float l0 = pl[row], l1 = pl[32768 + row];
    const float l2 = pl2[row], l3 = pl2[32768 + row];
    const float m = fmaxf(fmaxf(m0, m1), fmaxf(m2, m3));
    const float e0 = exp2f(m0 - m);
    const float e1 = exp2f(m1 - m);
    const float e2 = exp2f(m2 - m);
    const float e3 = exp2f(m3 - m);
    const float inv = 1.f / (l0 * e0 + l1 * e1 + l2 * e2 + l3 * e3);

    const ushort4 o0 = *(const ushort4*)&po[(size_t)row * 64 + cg];
    const ushort4 o1 = *(const ushort4*)&po[((size_t)32768 + row) * 64 + cg];
    const ushort4 o2 = *(const ushort4*)&po2[(size_t)row * 64 + cg];
    const ushort4 o3 = *(const ushort4*)&po2[((size_t)32768 + row) * 64 + cg];

    ushort4 r;
    r.x = f2bf((bf2f(o0.x) * e0 + bf2f(o1.x) * e1 + bf2f(o2.x) * e2 +
                bf2f(o3.x) * e3) * inv);
    r.y = f2bf((bf2f(o0.y) * e0 + bf2f(o1.y) * e1 + bf2f(o2.y) * e2 +
                bf2f(o3.y) * e3) * inv);
    r.z = f2bf((bf2f(o0.z) * e0 + bf2f(o1.z) * e1 + bf2f(o2.z) * e2 +
                bf2f(o3.z) * e3) * inv);
    r.w = f2bf((bf2f(o0.w) * e0 + bf2f(o1.w) * e1 + bf2f(o2.w) * e2 +
                bf2f(o3.w) * e3) * inv);
    *(ushort4*)&y[(size_t)(b * T_ + t) * C_ + 512 + h * 64 + cg] = r;
}

// ---------------------------------------------------------------------------
extern "C" void kernel_launch(void* const* d_in, const int* in_sizes, int n_in,
                              void* d_out, int out_size, void* d_ws,
                              size_t ws_size, hipStream_t stream) {
    const float* x         = (const float*)d_in[0];
    const float* Wqk_short = (const float*)d_in[1];
    const float* Wv_short  = (const float*)d_in[2];
    const float* Wqk_long  = (const float*)d_in[3];
    const float* Wv_long   = (const float*)d_in[4];
    const float* Wproj     = (const float*)d_in[5];
    float* out = (float*)d_out;

    const int M = B_ * T_;  // 4096

    // workspace layout (~75 MB)
    ushort* x16    = (ushort*)d_ws;                 // [4096][1024] bf16
    ushort* WallT  = x16 + (size_t)M * C_;          // [3584][1024] bf16
    ushort* WprojT = WallT + (size_t)NALL_ * C_;    // [1024][1024] bf16
    ushort* yb16   = WprojT + (size_t)C_ * C_;      // [4096][1024] bf16
    ushort* act    = yb16 + (size_t)M * C_;         // [4096][3584] bf16
    ushort* vt     = act + (size_t)M * NALL_;       // [32][64][2048] bf16
    ushort* po     = vt + (size_t)32 * HD_ * T_;    // [2][2][8][2048][64] bf16
    float*  pm     = (float*)(po + (size_t)2 * 32768 * 64);  // [2][32768]
    float*  pl     = pm + (size_t)2 * 32768;                 // [2][32768]

    // OVERLAYS for splits 2-3 (x16/WallT are dead after gemm1):
    // po2 needs 2*32768*64 ushorts = 8.39 MB = exactly x16's extent.
    ushort* po2 = x16;
    float*  pm2 = (float*)WallT;           // 2*32768 floats = 256 KB
    float*  pl2 = pm2 + (size_t)2 * 32768; // 2*32768 floats = 256 KB

    dim3 blk(256);
    prep<<<dim3(8704), blk, 0, stream>>>(x, x16, Wqk_short, Wv_short, Wqk_long,
                                         Wv_long, Wproj, WallT, WprojT);

    // input projection: 256x128 tiles @ 512 threads; QK tiles -> act,
    // V tiles transposed -> vt
    gemm_bf16<256, 128, 512, ushort, true>
        <<<dim3(NALL_ / 128, M / 256), dim3(512), 0, stream>>>(
            x16, WallT, act, vt, M, NALL_, C_);

    // Ks 64*(DL+8) + VTs 64*72 + Ps 128*72, bf16 -> 45056 B
    const int attn_lds = (64 * (DL_ + 8) + 64 * 72 + 128 * 72) * 2;
    attn_sched<<<dim3(1280), dim3(512), attn_lds, stream>>>(
        act, vt, yb16, po, pm, pl, po2, pm2, pl2);

    combine<<<dim3(2048), blk, 0, stream>>>(po, pm, pl, po2, pm2, pl2, yb16);

    // output projection: 64x64 tiles -> 1024 blocks (4/CU) for TLP
    gemm_bf16<64, 64, 256, float, false>
        <<<dim3(C_ / 64, M / 64), blk, 0, stream>>>(yb16, WprojT, out, nullptr,
                                                    M, C_, C_);
}

// Round 17
// 191.050 us; speedup vs baseline: 1.0627x; 1.0627x over previous
//
#include <hip/hip_runtime.h>
#include <math.h>

// Problem constants (match reference)
#define B_    2
#define T_    2048
#define C_    1024
#define HS_   8
#define DS_   32
#define HL_   8
#define DL_   128
#define HD_   64
#define WINS_ 256
#define WINL_ 1024
#define NALL_ 3584   // 512 (qk_s) + 512 (v_s) + 2048 (qk_l) + 512 (v_l)

typedef __bf16 bf16x8 __attribute__((ext_vector_type(8)));
typedef float floatx4 __attribute__((ext_vector_type(4)));

__device__ __forceinline__ ushort f2bf(float f) {
    union { float f; unsigned u; } v; v.f = f;
    unsigned r = v.u + 0x7fff + ((v.u >> 16) & 1);  // RNE
    return (ushort)(r >> 16);
}
__device__ __forceinline__ float bf2f(ushort u) {
    union { unsigned u; float f; } v; v.u = ((unsigned)u) << 16;
    return v.f;
}

// ---- DPP 16-lane butterfly reductions (VALU latency, no LDS) ----
#define DPP_STEP(x, ctrl, op)                                                \
    {                                                                        \
        float _t = __builtin_bit_cast(                                       \
            float, __builtin_amdgcn_update_dpp(                              \
                       0, __builtin_bit_cast(int, (x)), (ctrl), 0xf, 0xf,    \
                       true));                                               \
        (x) = op((x), _t);                                                   \
    }
__device__ __forceinline__ float dpp_max16(float x) {
    DPP_STEP(x, 0xB1, fmaxf);
    DPP_STEP(x, 0x4E, fmaxf);
    DPP_STEP(x, 0x141, fmaxf);
    DPP_STEP(x, 0x140, fmaxf);
    return x;
}
__device__ __forceinline__ float dpp_add16(float x) {
#define FADD_(a, b) ((a) + (b))
    DPP_STEP(x, 0xB1, FADD_);
    DPP_STEP(x, 0x4E, FADD_);
    DPP_STEP(x, 0x141, FADD_);
    DPP_STEP(x, 0x140, FADD_);
#undef FADD_
    return x;
}

// async global->LDS, 16B per lane. LDS dest = wave-uniform base + lane*16.
__device__ __forceinline__ void gload_lds16(const void* g, void* l) {
    __builtin_amdgcn_global_load_lds(
        (const __attribute__((address_space(1))) void*)g,
        (__attribute__((address_space(3))) void*)l, 16, 0, 0);
}

// ---------------------------------------------------------------------------
// Fused prep: blocks [0,4096) convert x fp32->bf16; blocks [4096,8704)
// transpose+convert the five weight matrices (K=1024 each).
// ---------------------------------------------------------------------------
__global__ __launch_bounds__(256) void prep(
    const float* __restrict__ x, ushort* __restrict__ x16,
    const float* __restrict__ Wqk_s, const float* __restrict__ Wv_s,
    const float* __restrict__ Wqk_l, const float* __restrict__ Wv_l,
    const float* __restrict__ Wproj, ushort* __restrict__ WallT,
    ushort* __restrict__ WprojT) {
    __shared__ float t[32][33];
    int bid = blockIdx.x;
    if (bid < 4096) {
        const int i = bid * 256 + threadIdx.x;
        float4 v = ((const float4*)x)[i];
        ushort4 o;
        o.x = f2bf(v.x); o.y = f2bf(v.y); o.z = f2bf(v.z); o.w = f2bf(v.w);
        ((ushort4*)x16)[i] = o;
        return;
    }
    bid -= 4096;
    const float* W; ushort* WT; int N, rowoff;
    if (bid < 512)       { W = Wqk_s; WT = WallT;  N = 512;  rowoff = 0; }
    else if (bid < 1024) { bid -= 512;  W = Wv_s;  WT = WallT;  N = 512;  rowoff = 512; }
    else if (bid < 3072) { bid -= 1024; W = Wqk_l; WT = WallT;  N = 2048; rowoff = 1024; }
    else if (bid < 3584) { bid -= 3072; W = Wv_l;  WT = WallT;  N = 512;  rowoff = 3072; }
    else                 { bid -= 3584; W = Wproj; WT = WprojT; N = 1024; rowoff = 0; }
    const int nt = N / 32;
    const int n0 = (bid % nt) * 32;
    const int k0 = (bid / nt) * 32;
    const int tx = threadIdx.x & 31;
    const int ty = threadIdx.x >> 5;  // 0..7
#pragma unroll
    for (int i = 0; i < 4; ++i)
        t[ty + 8 * i][tx] = W[(size_t)(k0 + ty + 8 * i) * N + n0 + tx];
    __syncthreads();
#pragma unroll
    for (int i = 0; i < 4; ++i)
        WT[(size_t)(rowoff + n0 + ty + 8 * i) * 1024 + k0 + tx] =
            f2bf(t[tx][ty + 8 * i]);
}

// ---------------------------------------------------------------------------
// bf16 MFMA GEMM: C[M,N] = A[M,K] bf16 @ BT[N,K] bf16.
// COUNTED-VMCNT PIPELINE (T4, m218): triple-buffered LDS, 2 K-tiles in
// flight; s_waitcnt vmcnt(NLD) + raw s_barrier per K-step (never drain 0).
//   gemm1: 256x128 @ 512T (R10 config). gemm2: 64x64 @ 256T (R9 config).
// NO XCD swizzle (R13: regression in this L3-fit regime).
// __launch_bounds__(TH,4) pins the 128-VGPR cap.
// FUSEV (input projection only): V-column tiles store TRANSPOSED into vt.
// ---------------------------------------------------------------------------
template <int BM, int BN, int TH, typename OT, bool FUSEV>
__global__ __launch_bounds__(TH, 4) void gemm_bf16(const ushort* __restrict__ A,
                                                   const ushort* __restrict__ BT,
                                                   OT* __restrict__ Cm,
                                                   ushort* __restrict__ VT,
                                                   int M, int N, int K) {
    // A rows [0,BM) then B rows [BM,BM+BN), each row 32 ushorts (one K-step)
    __shared__ ushort S[3][(BM + BN) * 32];
    constexpr int WM = TH / 128;             // waves along M (4 or 2)
    constexpr int NI = BM / WM / 16;         // per-wave M frags (4 or 2)
    constexpr int JB = BN / 32;              // per-wave N frags (4 or 2)
    constexpr int NLD = (BM + BN) * 4 / TH;  // gload_lds16 per thread/K-step

    const int tid = threadIdx.x;
    const int m0 = blockIdx.y * BM;
    const int n0 = blockIdx.x * BN;
    const int wave = tid >> 6;
    const int lane = tid & 63;
    const int wm = (wave >> 1) * (BM / WM);
    const int wn = (wave & 1) * (BN / 2);
    const int l15 = lane & 15;
    const int quad = lane >> 4;

    floatx4 acc[NI][JB] = {};

    // per-load staging base pointers (uniform branch per load index)
    const ushort* sbase[NLD];
#pragma unroll
    for (int i = 0; i < NLD; ++i) {
        const int idx = tid + TH * i;
        const int row = idx >> 2;
        const int ch = (idx & 3) * 8;
        sbase[i] = (row < BM) ? A + (size_t)(m0 + row) * K + ch
                              : BT + (size_t)(n0 + row - BM) * K + ch;
    }

#define STAGE(buf, kt)                                                      \
    {                                                                       \
        _Pragma("unroll") for (int i_ = 0; i_ < NLD; ++i_)                  \
            gload_lds16(sbase[i_] + (kt),                                   \
                        &S[buf][(wave * 64 + TH * i_) * 8]);                \
    }

#define COMPUTE(buf)                                                        \
    {                                                                       \
        bf16x8 af[NI], bfr[JB];                                             \
        _Pragma("unroll") for (int i = 0; i < NI; ++i) af[i] =              \
            *(const bf16x8*)&S[buf][(wm + i * 16 + l15) * 32 + quad * 8];   \
        _Pragma("unroll") for (int j = 0; j < JB; ++j) bfr[j] =             \
            *(const bf16x8*)&S[buf][(BM + wn + j * 16 + l15) * 32 +         \
                                    quad * 8];                              \
        _Pragma("unroll") for (int i = 0; i < NI; ++i)                      \
            _Pragma("unroll") for (int j = 0; j < JB; ++j) acc[i][j] =      \
                __builtin_amdgcn_mfma_f32_16x16x32_bf16(af[i], bfr[j],      \
                                                        acc[i][j], 0, 0, 0); \
    }

    // wait until only the NEWEST K-step's loads remain in flight
#define WAIT_CUR()                                                    \
    {                                                                 \
        if constexpr (NLD == 4)                                       \
            asm volatile("s_waitcnt vmcnt(4)" ::: "memory");          \
        else if constexpr (NLD == 3)                                  \
            asm volatile("s_waitcnt vmcnt(3)" ::: "memory");          \
        else                                                          \
            asm volatile("s_waitcnt vmcnt(2)" ::: "memory");          \
    }

    STAGE(0, 0);
    STAGE(1, 32);
    int cur = 0;
    for (int kt = 0; kt + 32 < K; kt += 32) {
        WAIT_CUR();
        __builtin_amdgcn_s_barrier();
        __builtin_amdgcn_sched_barrier(0);
        if (kt + 64 < K) {
            int nxt2 = cur + 2;
            if (nxt2 >= 3) nxt2 -= 3;
            STAGE(nxt2, kt + 64);
        }
        COMPUTE(cur);
        ++cur;
        if (cur == 3) cur = 0;
    }
    asm volatile("s_waitcnt vmcnt(0)" ::: "memory");
    __builtin_amdgcn_s_barrier();
    __builtin_amdgcn_sched_barrier(0);
    COMPUTE(cur);
#undef STAGE
#undef COMPUTE
#undef WAIT_CUR

    // ---- epilogue ----
    bool vtile = false;
    if constexpr (FUSEV)
        vtile = (n0 >= 512 && n0 < 1024) || (n0 >= 3072);

    if (FUSEV && vtile) {
        // transposed store into vt: row = b*1024 + vcol, col = t
#pragma unroll
        for (int i = 0; i < NI; ++i) {
            const int m = m0 + wm + i * 16 + quad * 4;
            const int bb = m >> 11;
            const int t = m & 2047;
#pragma unroll
            for (int j = 0; j < JB; ++j) {
                const int col = n0 + wn + j * 16 + l15;
                const int vcol = (col < 1024) ? (col - 512) : (col - 2560);
                ushort4 val;
                val.x = f2bf(acc[i][j][0]);
                val.y = f2bf(acc[i][j][1]);
                val.z = f2bf(acc[i][j][2]);
                val.w = f2bf(acc[i][j][3]);
                *(ushort4*)&VT[((size_t)(bb * 1024 + vcol)) * T_ + t] = val;
            }
        }
    } else {
#pragma unroll
        for (int i = 0; i < NI; ++i)
#pragma unroll
            for (int j = 0; j < JB; ++j)
#pragma unroll
                for (int r = 0; r < 4; ++r) {
                    const size_t idx =
                        (size_t)(m0 + wm + i * 16 + quad * 4 + r) * N + n0 +
                        wn + j * 16 + l15;
                    if constexpr (sizeof(OT) == 2)
                        Cm[idx] = f2bf(acc[i][j][r]);
                    else
                        Cm[idx] = acc[i][j][r];
                }
    }
}

// ---------------------------------------------------------------------------
// MFMA flash attention core — SESSION CHAMPION (192.91 us total):
// QBLK=128 / 8-wave, single K/V buffer (2 barriers/tile), defer-max, DPP
// softmax, 1-DEEP reg prefetch, Q direct global->reg, no setprio, 2-way
// long split. Falsified-and-closed levers (do not retry):
//  - 2-deep prefetch: R8 cap-spill; R14 SCRATCH-spill with VGPR_Count
//    unchanged (WRITE_SIZE is the spill tripwire, not VGPR_Count).
//  - K/V LDS double-buffer: R12 wash (barrier gain == occupancy loss).
//  - 4-way K-split: R16 regression (fixed per-block overhead doubled;
//    the 32% occupancy reading is steady-state latency stall, not tail).
//  - setprio/PSTR=76/XCD-swizzle: null or negative (R5/R13).
// Remaining headroom (attn: MfmaUtil 8%, HBM 16%) requires a new sync
// template (producer-consumer waves / 8-phase) -- out of verification
// budget for this harness.
// LDS: Ks 64*(D+8) | VTs 64*72 | Ps 128*72 -> 45056 B => 3 blocks/CU;
// 768 blocks x 512T fully co-resident, long (heavy) jobs first.
// ---------------------------------------------------------------------------
template <int D, int WIN, bool SPLIT>
__device__ __forceinline__ void attn_dev(
    const ushort* __restrict__ act, const ushort* __restrict__ vt,
    ushort* __restrict__ y, ushort* __restrict__ po, float* __restrict__ pm,
    float* __restrict__ pl, float scale2, int qoff, int koff, int head_off,
    int h, int gh, int b, int t0, int zs, ushort* lds) {
    constexpr int STR = D + 8;
    constexpr int VSTR = 72;
    constexpr int PSTR = 72;
    constexpr int NKS = D / 32;
    constexpr int QCH = D / 8;
    constexpr int KCH_TOT = 64 * QCH;            // 16B chunks in a K tile
    constexpr int NKLD = (KCH_TOT + 511) / 512;  // per-thread K loads

    ushort* Ks = lds;
    ushort* VTs = Ks + 64 * STR;
    ushort* Ps = VTs + 64 * VSTR;   // 128 rows

    const int tid = threadIdx.x;
    const int wave = tid >> 6;      // 0..7
    const int lane = tid & 63;
    const int l15 = lane & 15;
    const int quad = lane >> 4;
    const int qmin = t0 + wave * 16;

    int k0s = t0 - WIN + 1;
    if (k0s < 0) k0s = 0;
    k0s &= ~63;

    int ks_begin = k0s, ks_last = t0 + 64;  // queries span t0..t0+127
    if (SPLIT) {
        const int nt = ((t0 + 64 - k0s) >> 6) + 1;
        const int ntlo = (nt + 1) >> 1;
        if (zs == 0) {
            ks_last = k0s + (ntlo - 1) * 64;
        } else {
            if (ntlo >= nt) {  // empty split (dead for QBLK=128; kept safe)
#pragma unroll
                for (int r = 0; r < 4; ++r) {
                    const int t = qmin + quad * 4 + r;
                    const size_t ridx =
                        (((size_t)(zs * 2 + b) * 8 + h) * T_ + t);
                    if (l15 == 0) { pm[ridx] = -1e30f; pl[ridx] = 0.f; }
#pragma unroll
                    for (int j = 0; j < 4; ++j)
                        po[ridx * 64 + j * 16 + l15] = 0;
                }
                return;
            }
            ks_begin = k0s + ntlo * 64;
        }
    }

    const ushort* qbase = act + (size_t)(b * T_ + t0) * NALL_ + qoff + h * D;
    const ushort* kbase = act + (size_t)(b * T_) * NALL_ + koff + h * D;
    const ushort* vtb = vt + (size_t)((b * 16 + gh) * HD_) * T_;

    int krow[NKLD], kch[NKLD];
#pragma unroll
    for (int i = 0; i < NKLD; ++i) {
        const int idx = tid + 512 * i;
        krow[i] = idx / QCH;
        kch[i] = idx % QCH;
    }
    const int vd = tid >> 3, vc = (tid & 7) * 8;

    // ---- prefetch first tile into registers ----
    int4 kreg[NKLD], vreg;
#pragma unroll
    for (int i = 0; i < NKLD; ++i)
        if (tid + 512 * i < KCH_TOT)
            kreg[i] = *(const int4*)(kbase +
                                     (size_t)(ks_begin + krow[i]) * NALL_ +
                                     kch[i] * 8);
    vreg = *(const int4*)(vtb + (size_t)vd * T_ + ks_begin + vc);

    // ---- Q direct global -> registers (no LDS round-trip) ----
    bf16x8 qa[NKS];
#pragma unroll
    for (int ks = 0; ks < NKS; ++ks)
        qa[ks] = *(const bf16x8*)(qbase + (size_t)(wave * 16 + l15) * NALL_ +
                                  ks * 32 + quad * 8);

    float m_i[4], l_i[4];
    floatx4 o_acc[4] = {};
#pragma unroll
    for (int r = 0; r < 4; ++r) { m_i[r] = -1e30f; l_i[r] = 0.f; }

    for (int k0 = ks_begin; k0 <= ks_last; k0 += 64) {
        __syncthreads();  // all waves done reading Ks/VTs of prev tile
#pragma unroll
        for (int i = 0; i < NKLD; ++i)
            if (tid + 512 * i < KCH_TOT)
                *(int4*)&Ks[krow[i] * STR + kch[i] * 8] = kreg[i];
        *(int4*)&VTs[vd * VSTR + vc] = vreg;
        __syncthreads();
        if (k0 + 64 <= ks_last) {  // prefetch next tile (overlaps compute)
#pragma unroll
            for (int i = 0; i < NKLD; ++i)
                if (tid + 512 * i < KCH_TOT)
                    kreg[i] = *(const int4*)(kbase +
                                             (size_t)(k0 + 64 + krow[i]) *
                                                 NALL_ +
                                             kch[i] * 8);
            vreg = *(const int4*)(vtb + (size_t)vd * T_ + k0 + 64 + vc);
        }

        // ---- S = Q K^T ----
        floatx4 s[4] = {};
#pragma unroll
        for (int ks = 0; ks < NKS; ++ks) {
#pragma unroll
            for (int j = 0; j < 4; ++j) {
                const bf16x8 bb =
                    *(const bf16x8*)&Ks[(j * 16 + l15) * STR + ks * 32 + quad * 8];
                s[j] = __builtin_amdgcn_mfma_f32_16x16x32_bf16(qa[ks], bb, s[j],
                                                               0, 0, 0);
            }
        }

        // ---- scale (log2 domain) + mask ----
        const bool full = (k0 + 63 <= qmin) && ((qmin + 15) - k0 <= WIN - 1);
        if (full) {
#pragma unroll
            for (int j = 0; j < 4; ++j)
#pragma unroll
                for (int r = 0; r < 4; ++r) s[j][r] *= scale2;
        } else {
#pragma unroll
            for (int j = 0; j < 4; ++j) {
                const int kj = k0 + j * 16 + l15;
#pragma unroll
                for (int r = 0; r < 4; ++r) {
                    const int rel = (qmin + quad * 4 + r) - kj;
                    s[j][r] = (rel < 0 || rel >= WIN) ? -1e30f : s[j][r] * scale2;
                }
            }
        }

        // ---- online softmax (exp2 domain), DPP reductions, defer-max ----
        float rm[4];
#pragma unroll
        for (int r = 0; r < 4; ++r) {
            float t = fmaxf(fmaxf(s[0][r], s[1][r]), fmaxf(s[2][r], s[3][r]));
            rm[r] = dpp_max16(t);
        }
        const bool need = (rm[0] > m_i[0] + 8.f) || (rm[1] > m_i[1] + 8.f) ||
                          (rm[2] > m_i[2] + 8.f) || (rm[3] > m_i[3] + 8.f);
        if (__any(need)) {
#pragma unroll
            for (int r = 0; r < 4; ++r) {
                const float mn = fmaxf(m_i[r], rm[r]);
                const float a = exp2f(m_i[r] - mn);
                m_i[r] = mn;
                l_i[r] *= a;
#pragma unroll
                for (int j = 0; j < 4; ++j) o_acc[j][r] *= a;
            }
        }
#pragma unroll
        for (int r = 0; r < 4; ++r) {
            float sum = 0.f;
#pragma unroll
            for (int j = 0; j < 4; ++j) {
                const float e = exp2f(s[j][r] - m_i[r]);
                sum += e;
                Ps[(wave * 16 + quad * 4 + r) * PSTR + j * 16 + l15] = f2bf(e);
            }
            sum = dpp_add16(sum);
            l_i[r] += sum;
        }

        // ---- PV ----
#pragma unroll
        for (int kks = 0; kks < 2; ++kks) {
            const bf16x8 pa =
                *(const bf16x8*)&Ps[(wave * 16 + l15) * PSTR + kks * 32 + quad * 8];
#pragma unroll
            for (int j = 0; j < 4; ++j) {
                const bf16x8 vb =
                    *(const bf16x8*)&VTs[(j * 16 + l15) * VSTR + kks * 32 + quad * 8];
                o_acc[j] = __builtin_amdgcn_mfma_f32_16x16x32_bf16(pa, vb, o_acc[j],
                                                                   0, 0, 0);
            }
        }
    }

    // ---- epilogue ----
    if (SPLIT) {
#pragma unroll
        for (int r = 0; r < 4; ++r) {
            const int t = qmin + quad * 4 + r;
            const size_t ridx = (((size_t)(zs * 2 + b) * 8 + h) * T_ + t);
            if (l15 == 0) { pm[ridx] = m_i[r]; pl[ridx] = l_i[r]; }
#pragma unroll
            for (int j = 0; j < 4; ++j)
                po[ridx * 64 + j * 16 + l15] = f2bf(o_acc[j][r]);
        }
    } else {
#pragma unroll
        for (int r = 0; r < 4; ++r) {
            const float inv = 1.f / l_i[r];
            ushort* yrow = y + (size_t)(b * T_ + qmin + quad * 4 + r) * C_ +
                           head_off + h * HD_;
#pragma unroll
            for (int j = 0; j < 4; ++j)
                yrow[j * 16 + l15] = f2bf(o_acc[j][r] * inv);
        }
    }
}

// Sorted 1D job grid, QBLK=128: x<512 = long 2-way splits (t0 desc),
// x>=512 = short unsplit (t0 desc). 768 blocks @ 512T = 3/CU co-resident.
__global__ __launch_bounds__(512, 4) void attn_sched(
    const ushort* __restrict__ act, const ushort* __restrict__ vt,
    ushort* __restrict__ y, ushort* __restrict__ po, float* __restrict__ pm,
    float* __restrict__ pl) {
    extern __shared__ ushort smem[];
    int x = blockIdx.x;
    if (x < 512) {
        const int zs = x & 1;
        const int b = (x >> 1) & 1;
        const int h = (x >> 2) & 7;
        const int t0 = (15 - (x >> 5)) * 128;
        attn_dev<DL_, WINL_, true>(act, vt, y, po, pm, pl,
                                   0.12752021352994164f,  // 1/sqrt(128)*log2e
                                   1024, 2048, 512, h, 8 + h, b, t0, zs, smem);
    } else {
        x -= 512;
        const int b = x & 1;
        const int h = (x >> 1) & 7;
        const int t0 = (15 - (x >> 4)) * 128;
        attn_dev<DS_, WINS_, false>(act, vt, y, po, pm, pl,
                                    0.2550404270598833f,  // 1/sqrt(32)*log2e
                                    0, 256, 0, h, h, b, t0, 0, smem);
    }
}

// ---------------------------------------------------------------------------
// Flash-decoding combine for long heads: merge 2 splits' (o,m,l) -> yb16.
// exp2 domain. rows = [b][h][t] (32768); thread = one row x 4 cols.
// ---------------------------------------------------------------------------
__global__ __launch_bounds__(256) void combine(const ushort* __restrict__ po,
                                               const float* __restrict__ pm,
                                               const float* __restrict__ pl,
                                               ushort* __restrict__ y) {
    const int gid = blockIdx.x * 256 + threadIdx.x;
    const int row = gid >> 4;
    const int cg = (gid & 15) * 4;
    const int b = row >> 14;
    const int h = (row >> 11) & 7;
    const int t = row & 2047;

    const float m0 = pm[row], m1 = pm[32768 + row];
    const float l0 = pl[row], l1 = pl[32768 + row];
    const float m = fmaxf(m0, m1);
    const float e0 = exp2f(m0 - m);
    const float e1 = exp2f(m1 - m);
    const float inv = 1.f / (l0 * e0 + l1 * e1);

    const ushort4 o0 = *(const ushort4*)&po[(size_t)row * 64 + cg];
    const ushort4 o1 = *(const ushort4*)&po[((size_t)32768 + row) * 64 + cg];

    ushort4 r;
    r.x = f2bf((bf2f(o0.x) * e0 + bf2f(o1.x) * e1) * inv);
    r.y = f2bf((bf2f(o0.y) * e0 + bf2f(o1.y) * e1) * inv);
    r.z = f2bf((bf2f(o0.z) * e0 + bf2f(o1.z) * e1) * inv);
    r.w = f2bf((bf2f(o0.w) * e0 + bf2f(o1.w) * e1) * inv);
    *(ushort4*)&y[(size_t)(b * T_ + t) * C_ + 512 + h * 64 + cg] = r;
}

// ---------------------------------------------------------------------------
extern "C" void kernel_launch(void* const* d_in, const int* in_sizes, int n_in,
                              void* d_out, int out_size, void* d_ws,
                              size_t ws_size, hipStream_t stream) {
    const float* x         = (const float*)d_in[0];
    const float* Wqk_short = (const float*)d_in[1];
    const float* Wv_short  = (const float*)d_in[2];
    const float* Wqk_long  = (const float*)d_in[3];
    const float* Wv_long   = (const float*)d_in[4];
    const float* Wproj     = (const float*)d_in[5];
    float* out = (float*)d_out;

    const int M = B_ * T_;  // 4096

    // workspace layout (~75 MB)
    ushort* x16    = (ushort*)d_ws;                 // [4096][1024] bf16
    ushort* WallT  = x16 + (size_t)M * C_;          // [3584][1024] bf16
    ushort* WprojT = WallT + (size_t)NALL_ * C_;    // [1024][1024] bf16
    ushort* yb16   = WprojT + (size_t)C_ * C_;      // [4096][1024] bf16
    ushort* act    = yb16 + (size_t)M * C_;         // [4096][3584] bf16
    ushort* vt     = act + (size_t)M * NALL_;       // [32][64][2048] bf16
    ushort* po     = vt + (size_t)32 * HD_ * T_;    // [2][2][8][2048][64] bf16
    float*  pm     = (float*)(po + (size_t)2 * 32768 * 64);  // [2][32768]
    float*  pl     = pm + (size_t)2 * 32768;                 // [2][32768]

    dim3 blk(256);
    prep<<<dim3(8704), blk, 0, stream>>>(x, x16, Wqk_short, Wv_short, Wqk_long,
                                         Wv_long, Wproj, WallT, WprojT);

    // input projection: 256x128 tiles @ 512 threads; QK tiles -> act,
    // V tiles transposed -> vt
    gemm_bf16<256, 128, 512, ushort, true>
        <<<dim3(NALL_ / 128, M / 256), dim3(512), 0, stream>>>(
            x16, WallT, act, vt, M, NALL_, C_);

    // Ks 64*(DL+8) + VTs 64*72 + Ps 128*72, bf16 -> 45056 B
    const int attn_lds = (64 * (DL_ + 8) + 64 * 72 + 128 * 72) * 2;
    attn_sched<<<dim3(768), dim3(512), attn_lds, stream>>>(act, vt, yb16, po,
                                                           pm, pl);

    combine<<<dim3(2048), blk, 0, stream>>>(po, pm, pl, yb16);

    // output projection: 64x64 tiles -> 1024 blocks (4/CU) for TLP
    gemm_bf16<64, 64, 256, float, false>
        <<<dim3(C_ / 64, M / 64), blk, 0, stream>>>(yb16, WprojT, out, nullptr,
                                                    M, C_, C_);
}